// Round 8
// baseline (2095.343 us; speedup 1.0000x reference)
//
#include <hip/hip_runtime.h>

// ---------------- problem constants ----------------
constexpr int NY = 100, NX = 200;
constexpr int PML = 35;
constexpr int NYP = 170, NXP = 270;          // padded grid
constexpr int S = 2, NREC = 100, NT = 300;
constexpr float DX = 10.0f, DT = 1e-3f, DT2 = DT * DT;

// tiling: 2 shots x 16x8 tiles -> 256 blocks (one per CU)
constexpr int NTY = 16, NTX = 8;
constexpr int TY = 11, TX = 34;              // nominal tile (last row/col smaller)
constexpr int NBLKS = S * NTY * NTX;         // 256
constexpr int THREADS = 384;                 // 1 cell/thread (374 cells max), 6 waves

// LDS geometry: u is interior-only now (halo lives in registers)
constexpr int UW2 = TX;                      // 34 (34%32==2: contiguous wave reads)
constexpr int PYH = TY + 8;                  // 19 rows, stride TX
constexpr int PXW = 66;                      // px row stride (66%32==2)
constexpr int BXW = TX + 8;                  // 42

// packed strips: each halo cell is 8B {float value, int tag}; 3-slot ring
constexpr int CELLS_NS = 8 * TX;             // 272
constexpr int CELLS_WE = TY * 8;             // 88
constexpr int OFF_N = 0;
constexpr int OFF_S = CELLS_NS;              // 272
constexpr int OFF_W = 2 * CELLS_NS;          // 544
constexpr int OFF_E = 2 * CELLS_NS + CELLS_WE;  // 632
constexpr int STAGE_CELLS = 2 * CELLS_NS + 2 * CELLS_WE;  // 720 cells
constexpr int NSLOT = 3;

typedef unsigned long long u64;

// stencil coefficients, offsets -4..4, pre-scaled by 1/dx^2 and 1/dx
__device__ __constant__ float C2D[9] = {
    (float)(-1.0/560.0/100.0), (float)(8.0/315.0/100.0), (float)(-1.0/5.0/100.0),
    (float)(8.0/5.0/100.0),    (float)(-205.0/72.0/100.0), (float)(8.0/5.0/100.0),
    (float)(-1.0/5.0/100.0),   (float)(8.0/315.0/100.0),  (float)(-1.0/560.0/100.0)};
__device__ __constant__ float C1D[9] = {
    (float)(1.0/280.0/10.0), (float)(-4.0/105.0/10.0), (float)(1.0/5.0/10.0),
    (float)(-4.0/5.0/10.0),  0.0f,                     (float)(4.0/5.0/10.0),
    (float)(-1.0/5.0/10.0),  (float)(4.0/105.0/10.0),  (float)(-1.0/280.0/10.0)};

// ---------------- agent-scope accessors (coherent at Infinity Cache) -------
__device__ __forceinline__ u64 gload64(const u64* p) {
    return __hip_atomic_load(p, __ATOMIC_RELAXED, __HIP_MEMORY_SCOPE_AGENT);
}
__device__ __forceinline__ void gstore64(u64* p, u64 v) {
    __hip_atomic_store(p, v, __ATOMIC_RELAXED, __HIP_MEMORY_SCOPE_AGENT);
}

__device__ __forceinline__ float sigma_of(int d, int n, float smax) {
    float r = fmaxf(fmaxf((float)(PML - d) / (float)PML,
                          (float)(d - (n - 1 - PML)) / (float)PML), 0.0f);
    return smax * r * r;
}

// ---------------- setup: vmax -> sigma_max ----------------
__global__ void vmax_kernel(const float* __restrict__ vp, float* __restrict__ cst) {
    __shared__ float red[256];
    float m = 0.0f;
    for (int i = threadIdx.x; i < NY * NX; i += 256) m = fmaxf(m, vp[i]);
    red[threadIdx.x] = m;
    __syncthreads();
    for (int s2 = 128; s2 > 0; s2 >>= 1) {
        if (threadIdx.x < s2) red[threadIdx.x] = fmaxf(red[threadIdx.x], red[threadIdx.x + s2]);
        __syncthreads();
    }
    if (threadIdx.x == 0)
        cst[0] = 3.0f * red[0] * logf(1000.0f) / (2.0f * PML * DX);
}

// --- persistent kernel: direct-to-register halo, inline spin, 3-slot ring ---
__global__ __launch_bounds__(THREADS) void persist_kernel(
    const float* __restrict__ vp, const float* __restrict__ src,
    const int* __restrict__ src_loc, const int* __restrict__ rec_loc,
    float* __restrict__ out, u64* __restrict__ stage,
    const float* __restrict__ cst) {

    __shared__ float uS[2][TY * UW2];      // interior only; halo in registers
    __shared__ float pyS[2][PYH * TX];     // py double buffer
    __shared__ float pxS[2][TY * PXW];     // px double buffer
    __shared__ float byS[PYH], bymS[PYH], bxS[BXW], bxmS[BXW];
    __shared__ float srcS[NT];             // this shot's source wavelet

    const int tid = threadIdx.x;
    const int bid = blockIdx.x;
    const int sh  = bid / (NTY * NTX);
    const int tr  = bid - sh * (NTY * NTX);
    const int tyi = tr / NTX, txi = tr - tyi * NTX;
    const int y0 = tyi * TY, x0 = txi * TX;
    const int rows = min(TY, NYP - y0), cols = min(TX, NXP - x0);
    const float smax = cst[0];

    // zero LDS state
    for (int i = tid; i < 2 * TY * UW2; i += THREADS) ((float*)uS)[i] = 0.0f;
    for (int i = tid; i < 2 * PYH * TX; i += THREADS) ((float*)pyS)[i] = 0.0f;
    for (int i = tid; i < 2 * TY * PXW; i += THREADS) ((float*)pxS)[i] = 0.0f;

    if (tid < PYH) {
        int yy = y0 - 4 + tid;
        if (yy >= 0 && yy < NYP) {
            float b = __expf(-sigma_of(yy, NYP, smax) * DT);
            byS[tid] = b; bymS[tid] = b - 1.0f;
        } else { byS[tid] = 0.0f; bymS[tid] = 0.0f; }
    }
    if (tid < BXW) {
        int xx = x0 - 4 + tid;
        if (xx >= 0 && xx < NXP) {
            float b = __expf(-sigma_of(xx, NXP, smax) * DT);
            bxS[tid] = b; bxmS[tid] = b - 1.0f;
        } else { bxS[tid] = 0.0f; bxmS[tid] = 0.0f; }
    }

    // per-thread cell (t-invariant)
    const bool hasTask = (tid < rows * cols);
    const int y = hasTask ? tid / cols : 0;
    const int x = hasTask ? tid - y * cols : 0;

    // per-thread t-invariant physics coefficients
    float e_r = 0.0f, d_r = 0.0f, Av_r = 0.0f, Bv_r = 0.0f;
    if (hasTask) {
        int gy = y0 + y, gx = x0 + x;
        int vy = min(max(gy - PML, 0), NY - 1), vx = min(max(gx - PML, 0), NX - 1);
        float v = vp[vy * NX + vx];
        e_r = DT2 * v * v;
        float syv = sigma_of(gy, NYP, smax), sxv = sigma_of(gx, NXP, smax);
        d_r  = 1.0f / (1.0f + 0.5f * (syv + sxv) * DT);
        Av_r = 2.0f - syv * sxv * DT2;
        Bv_r = 1.0f - 0.5f * (syv + sxv) * DT;
    }

    // source; stage wavelet into LDS
    const int sy = src_loc[sh * 2 + 0] + PML, sx = src_loc[sh * 2 + 1] + PML;
    const bool ownSrc = (sy >= y0 && sy < y0 + rows && sx >= x0 && sx < x0 + cols);
    const bool isSrcThread = hasTask && ownSrc && (y == sy - y0) && (x == sx - x0);
    if (ownSrc)
        for (int i = tid; i < NT; i += THREADS) srcS[i] = src[sh * NT + i];

    // receiver
    int recLds = -1, recOut = 0;
    if (tid < S * NREC) {
        int rs = tid / NREC, rr2 = tid - rs * NREC;
        int ry = rec_loc[(rs * NREC + rr2) * 2 + 0] + PML;
        int rx = rec_loc[(rs * NREC + rr2) * 2 + 1] + PML;
        if (rs == sh && ry >= y0 && ry < y0 + rows && rx >= x0 && rx < x0 + cols) {
            recLds = (ry - y0) * UW2 + (rx - x0);
            recOut = rs * NT * NREC + rr2;
        }
    }

    const int bN = (tyi > 0)       ? bid - NTX : -1;
    const int bS = (tyi < NTY - 1) ? bid + NTX : -1;
    const int bW = (txi > 0)       ? bid - 1   : -1;
    const int bE = (txi < NTX - 1) ? bid + 1   : -1;
    const int rowsS_nb = (bS >= 0) ? min(TY, NYP - (y0 + TY)) : 0;

    // ---- per-thread direct-halo descriptors (t-invariant) ----
    // uc[i]      (i=0..7):  row y+i-8; N-halo iff i < 8-y
    // uc[9+i]    (i=0..7):  row y+i+1; S-halo iff row >= rows (and in S domain)
    // ur[i]      (i=0..7):  col x+i-8; W-halo iff i < 8-x
    // ur[9+i]    (i=0..7):  col x+i+1; E-halo iff col >= cols
    bool vN[8], vS[8], vW[8], vE[8];
    int  oN[8], oS[8], oW[8], oE[8];
#pragma unroll
    for (int i = 0; i < 8; i++) {
        vN[i] = hasTask && (i < 8 - y) && (bN >= 0);
        oN[i] = vN[i] ? bN * NSLOT * STAGE_CELLS + OFF_S + (y + i) * TX + x : 0;
        int rS2 = y + i + 1;
        vS[i] = hasTask && (rS2 >= rows) && (bS >= 0) && (rS2 - rows < rowsS_nb);
        oS[i] = vS[i] ? bS * NSLOT * STAGE_CELLS + OFF_N + (rS2 - rows) * TX + x : 0;
        vW[i] = hasTask && (i < 8 - x) && (bW >= 0);
        oW[i] = vW[i] ? bW * NSLOT * STAGE_CELLS + OFF_E + y * 8 + (x + i) : 0;
        int cE2 = x + i + 1;
        vE[i] = hasTask && (cE2 >= cols) && (bE >= 0);
        oE[i] = vE[i] ? bE * NSLOT * STAGE_CELLS + OFF_W + y * 8 + (cE2 - cols) : 0;
    }

    // ---- strip-push cell offsets (t-invariant) ----
    int aN = -1, aS = -1, aW = -1, aE = -1;
    if (hasTask) {
        if (y < 8)          aN = OFF_N + y * TX + x;
        if (y >= rows - 8)  aS = OFF_S + (y - (rows - 8)) * TX + x;
        if (x < 8)          aW = OFF_W + y * 8 + x;
        if (x >= cols - 8)  aE = OFF_E + y * 8 + (x - (cols - 8));
    }

    // prologue: publish u(0)=0 cells with tag=1 into slot 0
    {
        const u64 PK0 = ((u64)1 << 32);
        u64* s0 = stage + (size_t)bid * NSLOT * STAGE_CELLS;
        if (hasTask) {
            if (aN >= 0) gstore64(s0 + aN, PK0);
            if (aS >= 0) gstore64(s0 + aS, PK0);
            if (aW >= 0) gstore64(s0 + aW, PK0);
            if (aE >= 0) gstore64(s0 + aE, PK0);
        }
    }
    __syncthreads();

    float u_curr = 0.0f, u_prev = 0.0f;
    int pa = 0, pb = 0, slotR = 0, slotW = 1;

    for (int t = 0; t < NT; t++) {
        float* uCur = uS[pa];
        float* uN   = uS[pa ^ 1];
        const float* pyO = pyS[pb];
        float*       pyN = pyS[pb ^ 1];
        const float* pxO = pxS[pb];
        float*       pxN = pxS[pb ^ 1];

        __syncthreads();                       // the ONLY barrier per step

        // receivers sample u(t) = un(t-1)
        if (t > 0 && recLds >= 0) out[recOut + (t - 1) * NREC] = uCur[recLds];

        float unv = 0.0f, py0v = 0.0f, py4v = 0.0f, py8v = 0.0f;
        float px0v = 0.0f, px4v = 0.0f, px8v = 0.0f;
        if (hasTask) {
            const u64* sR = stage + (size_t)slotR * STAGE_CELLS;
            // ---- issue all halo loads (independent; pipelined) ----
            u64 hN[8], hS[8], hW[8], hE[8];
#pragma unroll
            for (int i = 0; i < 8; i++) {
                if (vN[i]) hN[i] = gload64(sR + oN[i]);
                if (vS[i]) hS[i] = gload64(sR + oS[i]);
                if (vW[i]) hW[i] = gload64(sR + oW[i]);
                if (vE[i]) hE[i] = gload64(sR + oE[i]);
            }
            // ---- spin: reload only stale cells (steady state: 0 iterations)
            const int need = t + 1;
            for (;;) {
                bool ok = true;
#pragma unroll
                for (int i = 0; i < 8; i++) {
                    if (vN[i] && (int)(hN[i] >> 32) < need) { hN[i] = gload64(sR + oN[i]); ok = false; }
                    if (vS[i] && (int)(hS[i] >> 32) < need) { hS[i] = gload64(sR + oS[i]); ok = false; }
                    if (vW[i] && (int)(hW[i] >> 32) < need) { hW[i] = gload64(sR + oW[i]); ok = false; }
                    if (vE[i] && (int)(hE[i] >> 32) < need) { hE[i] = gload64(sR + oE[i]); ok = false; }
                }
                if (ok) break;
            }

            // ---- assemble uc/ur (clamped LDS indices: safe under predication)
            float uc[17], ur[17];
#pragma unroll
            for (int i = 0; i < 8; i++) {
                int rc = max(y + i - 8, 0);
                uc[i] = (i < 8 - y) ? (vN[i] ? __uint_as_float((unsigned)hN[i]) : 0.0f)
                                    : uCur[rc * UW2 + x];
            }
            uc[8] = u_curr;
#pragma unroll
            for (int i = 0; i < 8; i++) {
                int r2 = y + i + 1;
                int rc = min(r2, TY - 1);
                uc[9 + i] = (r2 < rows) ? uCur[rc * UW2 + x]
                                        : (vS[i] ? __uint_as_float((unsigned)hS[i]) : 0.0f);
            }
#pragma unroll
            for (int i = 0; i < 8; i++) {
                int cc = max(x + i - 8, 0);
                ur[i] = (i < 8 - x) ? (vW[i] ? __uint_as_float((unsigned)hW[i]) : 0.0f)
                                    : uCur[y * UW2 + cc];
            }
            ur[8] = u_curr;
#pragma unroll
            for (int i = 0; i < 8; i++) {
                int c2 = x + i + 1;
                int cc = min(c2, TX - 1);
                ur[9 + i] = (c2 < cols) ? uCur[y * UW2 + cc]
                                        : (vE[i] ? __uint_as_float((unsigned)hE[i]) : 0.0f);
            }

            // ---- redundant CPML recompute (registers) ----
            float pyn[9], pxn[9];
#pragma unroll
            for (int j = 0; j < 9; j++) {
                float d1a = 0.0f, d1b = 0.0f;
#pragma unroll
                for (int k = 0; k < 4; k++) {
                    d1a = fmaf(C1D[k],     uc[j + k],     d1a);
                    d1b = fmaf(C1D[k + 5], uc[j + k + 5], d1b);
                }
                pyn[j] = fmaf(byS[y + j], pyO[(y + j) * TX + x],
                              bymS[y + j] * (d1a + d1b));
            }
#pragma unroll
            for (int j = 0; j < 9; j++) {
                float d1a = 0.0f, d1b = 0.0f;
#pragma unroll
                for (int k = 0; k < 4; k++) {
                    d1a = fmaf(C1D[k],     ur[j + k],     d1a);
                    d1b = fmaf(C1D[k + 5], ur[j + k + 5], d1b);
                }
                pxn[j] = fmaf(bxS[x + j], pxO[y * PXW + x + j],
                              bxmS[x + j] * (d1a + d1b));
            }

            float d2y = 0.0f, d2x = 0.0f, d1py = 0.0f, d1px = 0.0f;
#pragma unroll
            for (int k = 0; k < 9; k++) {
                d2y = fmaf(C2D[k], uc[4 + k], d2y);
                d2x = fmaf(C2D[k], ur[4 + k], d2x);
                if (k != 4) {
                    d1py = fmaf(C1D[k], pyn[k], d1py);
                    d1px = fmaf(C1D[k], pxn[k], d1px);
                }
            }
            const float lap = (d2y + d2x) + (d1py + d1px);
            const float f = isSrcThread ? srcS[t] : 0.0f;
            unv = (Av_r * u_curr - Bv_r * u_prev + e_r * (lap + f)) * d_r;

            // ---- early packed publish: {u(t+1), tag=t+2} into slot (t+1)%3
            u64* sb = stage + ((size_t)bid * NSLOT + slotW) * STAGE_CELLS;
            const u64 pk = ((u64)(unsigned)(t + 2) << 32) |
                           (u64)__float_as_uint(unv);
            if (aN >= 0) gstore64(sb + aN, pk);
            if (aS >= 0) gstore64(sb + aS, pk);
            if (aW >= 0) gstore64(sb + aW, pk);
            if (aE >= 0) gstore64(sb + aE, pk);

            py0v = pyn[0]; py4v = pyn[4]; py8v = pyn[8];
            px0v = pxn[0]; px4v = pxn[4]; px8v = pxn[8];
        }

        // ---- LDS state writes ----
        if (hasTask) {
            uN[y * UW2 + x] = unv;
            pyN[(y + 4) * TX + x] = py4v;
            if (y < 4)         pyN[y * TX + x]       = py0v;
            if (y >= rows - 4) pyN[(y + 8) * TX + x] = py8v;
            pxN[y * PXW + (x + 4)] = px4v;
            if (x < 4)         pxN[y * PXW + x]       = px0v;
            if (x >= cols - 4) pxN[y * PXW + (x + 8)] = px8v;
            u_prev = u_curr; u_curr = unv;
        }

        pa ^= 1; pb ^= 1;
        slotR = slotW; slotW = (slotW == 2) ? 0 : slotW + 1;
    }

    // epilogue: sample the last wavefield u(NT) = un(NT-1)
    __syncthreads();
    if (recLds >= 0) out[recOut + (NT - 1) * NREC] = uS[pa][recLds];
}

// ---------------- host launch ----------------
extern "C" void kernel_launch(void* const* d_in, const int* in_sizes, int n_in,
                              void* d_out, int out_size, void* d_ws, size_t ws_size,
                              hipStream_t stream) {
    const float* vp = (const float*)d_in[0];
    const float* src = (const float*)d_in[1];
    const int* src_loc = (const int*)d_in[2];
    const int* rec_loc = (const int*)d_in[3];
    float* out = (float*)d_out;

    float* ws = (float*)d_ws;
    float* cst = ws;                           // 32 floats (keeps stage 8B-aligned)
    u64* stage = (u64*)(ws + 32);              // NBLKS*3*STAGE_CELLS packed cells

    // zero cst + stage (tags=0; prologue publishes tag=1 cells into slot 0)
    hipMemsetAsync(d_ws, 0,
                   (size_t)32 * sizeof(float) +
                   (size_t)NBLKS * NSLOT * STAGE_CELLS * sizeof(u64),
                   stream);
    vmax_kernel<<<1, 256, 0, stream>>>(vp, cst);
    persist_kernel<<<NBLKS, THREADS, 0, stream>>>(
        vp, src, src_loc, rec_loc, out, stage, cst);
}

// Round 9
// 916.273 us; speedup vs baseline: 2.2868x; 2.2868x over previous
//
#include <hip/hip_runtime.h>

// ---------------- problem constants ----------------
constexpr int NY = 100, NX = 200;
constexpr int PML = 35;
constexpr int NYP = 170, NXP = 270;          // padded grid
constexpr int S = 2, NREC = 100, NT = 300;
constexpr float DX = 10.0f, DT = 1e-3f, DT2 = DT * DT;

// tiling: 2 shots x 16x16 tiles -> 512 blocks (two per CU)
constexpr int NTY = 16, NTX = 16;
constexpr int TY = 11, TX = 17;              // nominal tile (last row/col smaller)
constexpr int NBLKS = S * NTY * NTX;         // 512
constexpr int THREADS = 192;                 // 1 cell/thread (187 cells max), 3 waves

constexpr int UW = TX + 17;                  // 34 (34%32==2): u LDS row stride
constexpr int UH = TY + 16;                  // 27
constexpr int PYH = TY + 8;                  // 19: py rows [-4, rows+4), stride TX
constexpr int PXW = TX + 9;                  // 26: px cols [-4, cols+4) stride
constexpr int BXW = TX + 8;                  // 25 bx coefficient entries

// packed strips: each halo cell is 8B {float value, int tag} (single-copy atomic)
constexpr int CELLS_NS = 8 * TX;             // 136
constexpr int CELLS_WE = TY * 8;             // 88
constexpr int OFF_N = 0;
constexpr int OFF_S = CELLS_NS;              // 136
constexpr int OFF_W = 2 * CELLS_NS;          // 272
constexpr int OFF_E = 2 * CELLS_NS + CELLS_WE;  // 360
constexpr int STAGE_CELLS = 2 * CELLS_NS + 2 * CELLS_WE;  // 448 cells
constexpr int NE = 3;                        // halo descriptors per thread

typedef unsigned long long u64;

// stencil coefficients, offsets -4..4, pre-scaled by 1/dx^2 and 1/dx
__device__ __constant__ float C2D[9] = {
    (float)(-1.0/560.0/100.0), (float)(8.0/315.0/100.0), (float)(-1.0/5.0/100.0),
    (float)(8.0/5.0/100.0),    (float)(-205.0/72.0/100.0), (float)(8.0/5.0/100.0),
    (float)(-1.0/5.0/100.0),   (float)(8.0/315.0/100.0),  (float)(-1.0/560.0/100.0)};
__device__ __constant__ float C1D[9] = {
    (float)(1.0/280.0/10.0), (float)(-4.0/105.0/10.0), (float)(1.0/5.0/10.0),
    (float)(-4.0/5.0/10.0),  0.0f,                     (float)(4.0/5.0/10.0),
    (float)(-1.0/5.0/10.0),  (float)(4.0/105.0/10.0),  (float)(-1.0/280.0/10.0)};

// ---------------- agent-scope accessors (coherent at Infinity Cache) -------
__device__ __forceinline__ u64 gload64(const u64* p) {
    return __hip_atomic_load(p, __ATOMIC_RELAXED, __HIP_MEMORY_SCOPE_AGENT);
}
__device__ __forceinline__ void gstore64(u64* p, u64 v) {
    __hip_atomic_store(p, v, __ATOMIC_RELAXED, __HIP_MEMORY_SCOPE_AGENT);
}

__device__ __forceinline__ float sigma_of(int d, int n, float smax) {
    float r = fmaxf(fmaxf((float)(PML - d) / (float)PML,
                          (float)(d - (n - 1 - PML)) / (float)PML), 0.0f);
    return smax * r * r;
}

// ---------------- setup: vmax -> sigma_max ----------------
__global__ void vmax_kernel(const float* __restrict__ vp, float* __restrict__ cst) {
    __shared__ float red[256];
    float m = 0.0f;
    for (int i = threadIdx.x; i < NY * NX; i += 256) m = fmaxf(m, vp[i]);
    red[threadIdx.x] = m;
    __syncthreads();
    for (int s2 = 128; s2 > 0; s2 >>= 1) {
        if (threadIdx.x < s2) red[threadIdx.x] = fmaxf(red[threadIdx.x], red[threadIdx.x + s2]);
        __syncthreads();
    }
    if (threadIdx.x == 0)
        cst[0] = 3.0f * red[0] * logf(1000.0f) / (2.0f * PML * DX);
}

// ------- persistent kernel: single barrier/step, prefetched packed strips ---
__global__ __launch_bounds__(THREADS) void persist_kernel(
    const float* __restrict__ vp, const float* __restrict__ src,
    const int* __restrict__ src_loc, const int* __restrict__ rec_loc,
    float* __restrict__ out, u64* __restrict__ stage,
    const float* __restrict__ cst) {

    __shared__ float uS[2][UH * UW];       // u(t) / u(t-1)->u(t+1), swap each step
    __shared__ float pyS[2][PYH * TX];     // py double buffer
    __shared__ float pxS[2][TY * PXW];     // px double buffer
    __shared__ float byS[PYH], bymS[PYH], bxS[BXW], bxmS[BXW];
    __shared__ float srcS[NT];             // this shot's source wavelet

    const int tid = threadIdx.x;
    const int bid = blockIdx.x;
    const int sh  = bid / (NTY * NTX);
    const int tr  = bid - sh * (NTY * NTX);
    const int tyi = tr / NTX, txi = tr - tyi * NTX;
    const int y0 = tyi * TY, x0 = txi * TX;
    const int rows = min(TY, NYP - y0), cols = min(TX, NXP - x0);
    const float smax = cst[0];

    // zero LDS state (domain-boundary halos stay 0 forever)
    for (int i = tid; i < 2 * UH * UW; i += THREADS) ((float*)uS)[i] = 0.0f;
    for (int i = tid; i < 2 * PYH * TX; i += THREADS) ((float*)pyS)[i] = 0.0f;
    for (int i = tid; i < 2 * TY * PXW; i += THREADS) ((float*)pxS)[i] = 0.0f;

    if (tid < PYH) {
        int yy = y0 - 4 + tid;
        if (yy >= 0 && yy < NYP) {
            float b = __expf(-sigma_of(yy, NYP, smax) * DT);
            byS[tid] = b; bymS[tid] = b - 1.0f;
        } else { byS[tid] = 0.0f; bymS[tid] = 0.0f; }
    }
    if (tid < BXW) {
        int xx = x0 - 4 + tid;
        if (xx >= 0 && xx < NXP) {
            float b = __expf(-sigma_of(xx, NXP, smax) * DT);
            bxS[tid] = b; bxmS[tid] = b - 1.0f;
        } else { bxS[tid] = 0.0f; bxmS[tid] = 0.0f; }
    }

    // per-thread cell (t-invariant): 1 cell per thread
    const bool hasTask = (tid < rows * cols);
    const int y = hasTask ? tid / cols : 0;
    const int x = hasTask ? tid - y * cols : 0;

    // per-thread t-invariant physics coefficients (registers, not LDS)
    float e_r = 0.0f, d_r = 0.0f, Av_r = 0.0f, Bv_r = 0.0f;
    if (hasTask) {
        int gy = y0 + y, gx = x0 + x;
        int vy = min(max(gy - PML, 0), NY - 1), vx = min(max(gx - PML, 0), NX - 1);
        float v = vp[vy * NX + vx];
        e_r = DT2 * v * v;
        float syv = sigma_of(gy, NYP, smax), sxv = sigma_of(gx, NXP, smax);
        d_r  = 1.0f / (1.0f + 0.5f * (syv + sxv) * DT);
        Av_r = 2.0f - syv * sxv * DT2;
        Bv_r = 1.0f - 0.5f * (syv + sxv) * DT;
    }

    // source (NSRC == 1 per shot); stage wavelet into LDS
    const int sy = src_loc[sh * 2 + 0] + PML, sx = src_loc[sh * 2 + 1] + PML;
    const bool ownSrc = (sy >= y0 && sy < y0 + rows && sx >= x0 && sx < x0 + cols);
    const bool isSrcThread = hasTask && ownSrc && (y == sy - y0) && (x == sx - x0);
    if (ownSrc)
        for (int i = tid; i < NT; i += THREADS) srcS[i] = src[sh * NT + i];

    // receivers: thread handles up to 2 (200 receivers > 192 threads)
    int recLds[2] = {-1, -1}, recOut[2] = {0, 0};
#pragma unroll
    for (int r = 0; r < 2; r++) {
        int idx = tid + r * THREADS;
        if (idx < S * NREC) {
            int rs = idx / NREC, rr2 = idx - rs * NREC;
            int ry = rec_loc[(rs * NREC + rr2) * 2 + 0] + PML;
            int rx = rec_loc[(rs * NREC + rr2) * 2 + 1] + PML;
            if (rs == sh && ry >= y0 && ry < y0 + rows && rx >= x0 && rx < x0 + cols) {
                recLds[r] = (ry - y0 + 8) * UW + (rx - x0 + 8);
                recOut[r] = rs * NT * NREC + rr2;
            }
        }
    }

    const int bN = (tyi > 0)       ? bid - NTX : -1;
    const int bS = (tyi < NTY - 1) ? bid + NTX : -1;
    const int bW = (txi > 0)       ? bid - 1   : -1;
    const int bE = (txi < NTX - 1) ? bid + 1   : -1;

    const int nNS = 8 * cols, nWE = rows * 8;
    const int nTot = 2 * nNS + 2 * nWE;       // <= 448 <= NE*THREADS

    // ---- precompute the NE halo-read descriptors per thread (t-invariant) --
    int hLds[NE], hSrc[NE];
#pragma unroll
    for (int e = 0; e < NE; e++) { hLds[e] = -1; hSrc[e] = 0; }
#pragma unroll
    for (int e = 0; e < NE; e++) {
        int i = tid + e * THREADS;
        if (i >= nTot) continue;
        int j = i, nb = -1, o = 0, lds = -1;
        if (j < nNS) {                         // from N neighbor's S strip
            nb = bN;
            int r2 = j / cols, c2 = j - r2 * cols;
            o = OFF_S + r2 * TX + c2;          // N nb always has rows==TY>=8
            lds = r2 * UW + 8 + c2;
        } else if ((j -= nNS) < nNS) {         // from S neighbor's N strip
            nb = bS;
            int r2 = j / cols, c2 = j - r2 * cols;
            if (nb >= 0) {
                int rowsS = min(TY, NYP - (y0 + TY));  // S nb row count
                if (r2 >= rowsS) nb = -1;      // out-of-domain: stays 0
            }
            o = OFF_N + r2 * TX + c2;
            lds = (8 + rows + r2) * UW + 8 + c2;
        } else if ((j -= nNS) < nWE) {         // from W neighbor's E strip
            nb = bW;
            o = OFF_E + j;
            lds = (8 + (j >> 3)) * UW + (j & 7);
        } else {                               // from E neighbor's W strip
            j -= nWE;
            nb = bE;
            o = OFF_W + j;
            lds = (8 + (j >> 3)) * UW + 8 + cols + (j & 7);
        }
        if (nb < 0) continue;
        hLds[e] = lds;
        hSrc[e] = nb * 2 * STAGE_CELLS + o;
    }
    bool nv[NE];
    const u64* sA[NE];
#pragma unroll
    for (int e = 0; e < NE; e++) { nv[e] = (hLds[e] >= 0); sA[e] = stage + hSrc[e]; }

    // ---- precompute strip-push cell offsets for own cell (t-invariant) ----
    int aN = -1, aS = -1, aW = -1, aE = -1;
    if (hasTask) {
        if (y < 8)          aN = OFF_N + y * TX + x;
        if (y >= rows - 8)  aS = OFF_S + (y - (rows - 8)) * TX + x;
        if (x < 8)          aW = OFF_W + y * 8 + x;
        if (x >= cols - 8)  aE = OFF_E + y * 8 + (x - (cols - 8));
    }

    // prologue: publish u(0)=0 cells with tag=1 into parity-0 slot
    {
        const u64 PK0 = ((u64)1 << 32);        // value bits 0.0f, tag 1
        u64* s0 = stage + (size_t)(bid * 2 + 0) * STAGE_CELLS;
        if (hasTask) {
            if (aN >= 0) gstore64(s0 + aN, PK0);
            if (aS >= 0) gstore64(s0 + aS, PK0);
            if (aW >= 0) gstore64(s0 + aW, PK0);
            if (aE >= 0) gstore64(s0 + aE, PK0);
        }
    }
    __syncthreads();

    // prefetch for t=0 (parity-0 slot)
    u64 pf[NE];
#pragma unroll
    for (int e = 0; e < NE; e++) pf[e] = nv[e] ? gload64(sA[e]) : 0;

    float u_curr = 0.0f, u_prev = 0.0f;        // this cell's u(t), u(t-1)

    int pa = 0, pb = 0;
    for (int t = 0; t < NT; t++) {
        const int par = t & 1;                 // slot holding u(t) strips
        float* uCur = uS[pa];
        float* uN   = uS[pa ^ 1];
        const float* pyO = pyS[pb];
        float*       pyN = pyS[pb ^ 1];
        const float* pxO = pxS[pb];
        float*       pxN = pxS[pb ^ 1];

        // ---- 1. spin on prefetched packed cells; write halo to LDS ----
        {
            const int need = t + 1;
            for (;;) {
                bool ok = true;
#pragma unroll
                for (int e = 0; e < NE; e++)
                    if (nv[e] && (int)(pf[e] >> 32) < need) {
                        pf[e] = gload64(sA[e] + (size_t)par * STAGE_CELLS);
                        ok = false;
                    }
                if (ok) break;
            }
#pragma unroll
            for (int e = 0; e < NE; e++)
                if (nv[e]) uCur[hLds[e]] = __uint_as_float((unsigned)pf[e]);
        }
        __syncthreads();                       // the ONLY barrier per step

        // ---- 2. receivers sample u(t) = un(t-1) ----
        if (t > 0) {
#pragma unroll
            for (int r = 0; r < 2; r++)
                if (recLds[r] >= 0) out[recOut[r] + (t - 1) * NREC] = uCur[recLds[r]];
        }

        // ---- 3. fused compute + early publish ----
        u64* sb = stage + (size_t)(bid * 2 + (par ^ 1)) * STAGE_CELLS;
        float unv = 0.0f, py0v = 0.0f, py4v = 0.0f, py8v = 0.0f;
        float px0v = 0.0f, px4v = 0.0f, px8v = 0.0f;
        if (hasTask) {
            float uc[17], ur[17];
#pragma unroll
            for (int j = 0; j < 17; j++)
                uc[j] = (j == 8) ? u_curr : uCur[(y + j) * UW + 8 + x];
#pragma unroll
            for (int k = 0; k < 17; k++)
                ur[k] = (k == 8) ? u_curr : uCur[(8 + y) * UW + x + k];

            float pyn[9], pxn[9];
#pragma unroll
            for (int j = 0; j < 9; j++) {
                float d1a = 0.0f, d1b = 0.0f;
#pragma unroll
                for (int k = 0; k < 4; k++) {
                    d1a = fmaf(C1D[k],     uc[j + k],     d1a);
                    d1b = fmaf(C1D[k + 5], uc[j + k + 5], d1b);
                }
                pyn[j] = fmaf(byS[y + j], pyO[(y + j) * TX + x],
                              bymS[y + j] * (d1a + d1b));
            }
#pragma unroll
            for (int j = 0; j < 9; j++) {
                float d1a = 0.0f, d1b = 0.0f;
#pragma unroll
                for (int k = 0; k < 4; k++) {
                    d1a = fmaf(C1D[k],     ur[j + k],     d1a);
                    d1b = fmaf(C1D[k + 5], ur[j + k + 5], d1b);
                }
                pxn[j] = fmaf(bxS[x + j], pxO[y * PXW + x + j],
                              bxmS[x + j] * (d1a + d1b));
            }

            float d2y = 0.0f, d2x = 0.0f, d1py = 0.0f, d1px = 0.0f;
#pragma unroll
            for (int k = 0; k < 9; k++) {
                d2y = fmaf(C2D[k], uc[4 + k], d2y);
                d2x = fmaf(C2D[k], ur[4 + k], d2x);
                if (k != 4) {
                    d1py = fmaf(C1D[k], pyn[k], d1py);
                    d1px = fmaf(C1D[k], pxn[k], d1px);
                }
            }
            const float lap = (d2y + d2x) + (d1py + d1px);
            const float f = isSrcThread ? srcS[t] : 0.0f;
            unv = (Av_r * u_curr - Bv_r * u_prev + e_r * (lap + f)) * d_r;

            // early packed publish: {u(t+1), tag=t+2} straight from register
            const u64 pk = ((u64)(unsigned)(t + 2) << 32) |
                           (u64)__float_as_uint(unv);
            if (aN >= 0) gstore64(sb + aN, pk);
            if (aS >= 0) gstore64(sb + aS, pk);
            if (aW >= 0) gstore64(sb + aW, pk);
            if (aE >= 0) gstore64(sb + aE, pk);

            py0v = pyn[0]; py4v = pyn[4]; py8v = pyn[8];
            px0v = pxn[0]; px4v = pxn[4]; px8v = pxn[8];
        }

        // ---- 4. prefetch next slot (overlaps MALL RT with LDS writes) ----
#pragma unroll
        for (int e = 0; e < NE; e++)
            if (nv[e]) pf[e] = gload64(sA[e] + (size_t)(par ^ 1) * STAGE_CELLS);

        // ---- 5. LDS state writes ----
        if (hasTask) {
            uN[(8 + y) * UW + 8 + x] = unv;
            pyN[(y + 4) * TX + x] = py4v;
            if (y < 4)         pyN[y * TX + x]       = py0v;
            if (y >= rows - 4) pyN[(y + 8) * TX + x] = py8v;
            pxN[y * PXW + (x + 4)] = px4v;
            if (x < 4)         pxN[y * PXW + x]       = px0v;
            if (x >= cols - 4) pxN[y * PXW + (x + 8)] = px8v;
            u_prev = u_curr; u_curr = unv;
        }

        pa ^= 1; pb ^= 1;
    }

    // epilogue: sample the last wavefield u(NT) = un(NT-1)
    __syncthreads();
#pragma unroll
    for (int r = 0; r < 2; r++)
        if (recLds[r] >= 0) out[recOut[r] + (NT - 1) * NREC] = uS[pa][recLds[r]];
}

// ---------------- host launch ----------------
extern "C" void kernel_launch(void* const* d_in, const int* in_sizes, int n_in,
                              void* d_out, int out_size, void* d_ws, size_t ws_size,
                              hipStream_t stream) {
    const float* vp = (const float*)d_in[0];
    const float* src = (const float*)d_in[1];
    const int* src_loc = (const int*)d_in[2];
    const int* rec_loc = (const int*)d_in[3];
    float* out = (float*)d_out;

    float* ws = (float*)d_ws;
    float* cst = ws;                           // 32 floats (keeps stage 8B-aligned)
    u64* stage = (u64*)(ws + 32);              // NBLKS*2*STAGE_CELLS packed cells

    // zero cst + stage (tags=0; prologue publishes tag=1 cells into slot 0)
    hipMemsetAsync(d_ws, 0,
                   (size_t)32 * sizeof(float) +
                   (size_t)NBLKS * 2 * STAGE_CELLS * sizeof(u64),
                   stream);
    vmax_kernel<<<1, 256, 0, stream>>>(vp, cst);
    persist_kernel<<<NBLKS, THREADS, 0, stream>>>(
        vp, src, src_loc, rec_loc, out, stage, cst);
}

// Round 10
// 760.907 us; speedup vs baseline: 2.7537x; 1.2042x over previous
//
#include <hip/hip_runtime.h>

// ---------------- problem constants ----------------
constexpr int NY = 100, NX = 200;
constexpr int PML = 35;
constexpr int NYP = 170, NXP = 270;          // padded grid
constexpr int S = 2, NREC = 100, NT = 300;
constexpr float DX = 10.0f, DT = 1e-3f, DT2 = DT * DT;

// tiling: 2 shots x 16x8 tiles -> 256 blocks (one per CU)
constexpr int NTY = 16, NTX = 8;
constexpr int TY = 11, TX = 34;              // nominal tile (last row/col smaller)
constexpr int NBLKS = S * NTY * NTX;         // 256
constexpr int THREADS = 768;                 // 2 threads per cell, 12 waves/CU

// bank-friendly LDS strides (stride % 32 == 2)
constexpr int UW = 66;                       // u row stride (>= TX+16 = 50)
constexpr int UH = TY + 16;                  // 27
constexpr int PYH = TY + 8;                  // 19 rows; stride TX=34 (34%32==2)
constexpr int PXW = 66;                      // px row stride (>= cols+8 = 42)
constexpr int BXW = TX + 8;                  // 42

// packed strips: each halo cell is 8B {float value, int tag} (single-copy atomic)
constexpr int CELLS_NS = 8 * TX;             // 272
constexpr int CELLS_WE = TY * 8;             // 88
constexpr int OFF_N = 0;
constexpr int OFF_S = CELLS_NS;              // 272
constexpr int OFF_W = 2 * CELLS_NS;          // 544
constexpr int OFF_E = 2 * CELLS_NS + CELLS_WE;  // 632
constexpr int STAGE_CELLS = 2 * CELLS_NS + 2 * CELLS_WE;  // 720 cells

typedef unsigned long long u64;

// stencil coefficients, offsets -4..4, pre-scaled by 1/dx^2 and 1/dx
__device__ __constant__ float C2D[9] = {
    (float)(-1.0/560.0/100.0), (float)(8.0/315.0/100.0), (float)(-1.0/5.0/100.0),
    (float)(8.0/5.0/100.0),    (float)(-205.0/72.0/100.0), (float)(8.0/5.0/100.0),
    (float)(-1.0/5.0/100.0),   (float)(8.0/315.0/100.0),  (float)(-1.0/560.0/100.0)};
__device__ __constant__ float C1D[9] = {
    (float)(1.0/280.0/10.0), (float)(-4.0/105.0/10.0), (float)(1.0/5.0/10.0),
    (float)(-4.0/5.0/10.0),  0.0f,                     (float)(4.0/5.0/10.0),
    (float)(-1.0/5.0/10.0),  (float)(4.0/105.0/10.0),  (float)(-1.0/280.0/10.0)};

// ---------------- agent-scope accessors (coherent at Infinity Cache) -------
__device__ __forceinline__ u64 gload64(const u64* p) {
    return __hip_atomic_load(p, __ATOMIC_RELAXED, __HIP_MEMORY_SCOPE_AGENT);
}
__device__ __forceinline__ void gstore64(u64* p, u64 v) {
    __hip_atomic_store(p, v, __ATOMIC_RELAXED, __HIP_MEMORY_SCOPE_AGENT);
}

__device__ __forceinline__ float sigma_of(int d, int n, float smax) {
    float r = fmaxf(fmaxf((float)(PML - d) / (float)PML,
                          (float)(d - (n - 1 - PML)) / (float)PML), 0.0f);
    return smax * r * r;
}

// ---------------- setup: vmax -> sigma_max ----------------
__global__ void vmax_kernel(const float* __restrict__ vp, float* __restrict__ cst) {
    __shared__ float red[256];
    float m = 0.0f;
    for (int i = threadIdx.x; i < NY * NX; i += 256) m = fmaxf(m, vp[i]);
    red[threadIdx.x] = m;
    __syncthreads();
    for (int s2 = 128; s2 > 0; s2 >>= 1) {
        if (threadIdx.x < s2) red[threadIdx.x] = fmaxf(red[threadIdx.x], red[threadIdx.x + s2]);
        __syncthreads();
    }
    if (threadIdx.x == 0)
        cst[0] = 3.0f * red[0] * logf(1000.0f) / (2.0f * PML * DX);
}

// -- persistent kernel: lane-pair split cells, single barrier, packed strips --
__global__ __launch_bounds__(THREADS) void persist_kernel(
    const float* __restrict__ vp, const float* __restrict__ src,
    const int* __restrict__ src_loc, const int* __restrict__ rec_loc,
    float* __restrict__ out, u64* __restrict__ stage,
    const float* __restrict__ cst) {

    __shared__ float uS[2][UH * UW];       // u(t) / u(t-1)->u(t+1), swap each step
    __shared__ float pyS[2][PYH * TX];     // py double buffer
    __shared__ float pxS[2][TY * PXW];     // px double buffer
    __shared__ float byS[PYH], bymS[PYH], bxS[BXW], bxmS[BXW];
    __shared__ float srcS[NT];             // this shot's source wavelet

    const int tid = threadIdx.x;
    const int bid = blockIdx.x;
    const int sh  = bid / (NTY * NTX);
    const int tr  = bid - sh * (NTY * NTX);
    const int tyi = tr / NTX, txi = tr - tyi * NTX;
    const int y0 = tyi * TY, x0 = txi * TX;
    const int rows = min(TY, NYP - y0), cols = min(TX, NXP - x0);
    const float smax = cst[0];

    // zero LDS state (domain-boundary halos stay 0 forever)
    for (int i = tid; i < 2 * UH * UW; i += THREADS) ((float*)uS)[i] = 0.0f;
    for (int i = tid; i < 2 * PYH * TX; i += THREADS) ((float*)pyS)[i] = 0.0f;
    for (int i = tid; i < 2 * TY * PXW; i += THREADS) ((float*)pxS)[i] = 0.0f;

    if (tid < PYH) {
        int yy = y0 - 4 + tid;
        if (yy >= 0 && yy < NYP) {
            float b = __expf(-sigma_of(yy, NYP, smax) * DT);
            byS[tid] = b; bymS[tid] = b - 1.0f;
        } else { byS[tid] = 0.0f; bymS[tid] = 0.0f; }
    }
    if (tid < BXW) {
        int xx = x0 - 4 + tid;
        if (xx >= 0 && xx < NXP) {
            float b = __expf(-sigma_of(xx, NXP, smax) * DT);
            bxS[tid] = b; bxmS[tid] = b - 1.0f;
        } else { bxS[tid] = 0.0f; bxmS[tid] = 0.0f; }
    }

    // lane-pair cell mapping: threads 2c (role 0: column) / 2c+1 (role 1: row)
    const int role = tid & 1;
    const int cell = tid >> 1;
    const bool hasTask = (tid < 2 * rows * cols);
    const int y = hasTask ? cell / cols : 0;
    const int x = hasTask ? cell - y * cols : 0;

    // per-thread t-invariant physics coefficients (role 0 only)
    float e_r = 0.0f, d_r = 0.0f, Av_r = 0.0f, Bv_r = 0.0f;
    if (hasTask && role == 0) {
        int gy = y0 + y, gx = x0 + x;
        int vy = min(max(gy - PML, 0), NY - 1), vx = min(max(gx - PML, 0), NX - 1);
        float v = vp[vy * NX + vx];
        e_r = DT2 * v * v;
        float syv = sigma_of(gy, NYP, smax), sxv = sigma_of(gx, NXP, smax);
        d_r  = 1.0f / (1.0f + 0.5f * (syv + sxv) * DT);
        Av_r = 2.0f - syv * sxv * DT2;
        Bv_r = 1.0f - 0.5f * (syv + sxv) * DT;
    }

    // source (NSRC == 1 per shot); stage wavelet into LDS
    const int sy = src_loc[sh * 2 + 0] + PML, sx = src_loc[sh * 2 + 1] + PML;
    const bool ownSrc = (sy >= y0 && sy < y0 + rows && sx >= x0 && sx < x0 + cols);
    const bool isSrc = hasTask && (role == 0) && ownSrc &&
                       (y == sy - y0) && (x == sx - x0);
    if (ownSrc)
        for (int i = tid; i < NT; i += THREADS) srcS[i] = src[sh * NT + i];

    // receiver: thread tid handles global receiver tid (<=1 per thread)
    int recLds = -1, recOut = 0;
    if (tid < S * NREC) {
        int rs = tid / NREC, rr2 = tid - rs * NREC;
        int ry = rec_loc[(rs * NREC + rr2) * 2 + 0] + PML;
        int rx = rec_loc[(rs * NREC + rr2) * 2 + 1] + PML;
        if (rs == sh && ry >= y0 && ry < y0 + rows && rx >= x0 && rx < x0 + cols) {
            recLds = (ry - y0 + 8) * UW + (rx - x0 + 8);
            recOut = rs * NT * NREC + rr2;
        }
    }

    const int bN = (tyi > 0)       ? bid - NTX : -1;
    const int bS = (tyi < NTY - 1) ? bid + NTX : -1;
    const int bW = (txi > 0)       ? bid - 1   : -1;
    const int bE = (txi < NTX - 1) ? bid + 1   : -1;

    const int nNS = 8 * cols, nWE = rows * 8;
    const int nTot = 2 * nNS + 2 * nWE;       // <= 720 <= THREADS

    // ---- single halo-read descriptor per thread (t-invariant) ----
    int hLds = -1, hSrc = 0;
    if (tid < nTot) {
        int j = tid, nb = -1, o = 0, lds = -1;
        if (j < nNS) {                         // from N neighbor's S strip
            nb = bN;
            int r2 = j / cols, c2 = j - r2 * cols;
            o = OFF_S + r2 * TX + c2;          // N nb always has rows==TY>=8
            lds = r2 * UW + 8 + c2;
        } else if ((j -= nNS) < nNS) {         // from S neighbor's N strip
            nb = bS;
            int r2 = j / cols, c2 = j - r2 * cols;
            if (nb >= 0) {
                int rowsS = min(TY, NYP - (y0 + TY));
                if (r2 >= rowsS) nb = -1;      // out-of-domain: stays 0
            }
            o = OFF_N + r2 * TX + c2;
            lds = (8 + rows + r2) * UW + 8 + c2;
        } else if ((j -= nNS) < nWE) {         // from W neighbor's E strip
            nb = bW;
            o = OFF_E + j;
            lds = (8 + (j >> 3)) * UW + (j & 7);
        } else {                               // from E neighbor's W strip
            j -= nWE;
            nb = bE;
            o = OFF_W + j;
            lds = (8 + (j >> 3)) * UW + 8 + cols + (j & 7);
        }
        if (nb >= 0) { hLds = lds; hSrc = nb * 2 * STAGE_CELLS + o; }
    }
    const bool nv = (hLds >= 0);
    const u64* sA = stage + hSrc;

    // ---- strip-push cell offsets (role 0 only, t-invariant) ----
    int aN = -1, aS = -1, aW = -1, aE = -1;
    if (hasTask && role == 0) {
        if (y < 8)          aN = OFF_N + y * TX + x;
        if (y >= rows - 8)  aS = OFF_S + (y - (rows - 8)) * TX + x;
        if (x < 8)          aW = OFF_W + y * 8 + x;
        if (x >= cols - 8)  aE = OFF_E + y * 8 + (x - (cols - 8));
    }

    // prologue: publish u(0)=0 cells with tag=1 into parity-0 slot
    {
        const u64 PK0 = ((u64)1 << 32);
        u64* s0 = stage + (size_t)(bid * 2 + 0) * STAGE_CELLS;
        if (aN >= 0) gstore64(s0 + aN, PK0);
        if (aS >= 0) gstore64(s0 + aS, PK0);
        if (aW >= 0) gstore64(s0 + aW, PK0);
        if (aE >= 0) gstore64(s0 + aE, PK0);
    }
    __syncthreads();

    // prefetch for t=0 (parity-0 slot)
    u64 pf = nv ? gload64(sA) : 0;

    float u_curr = 0.0f, u_prev = 0.0f;        // this cell's u(t), u(t-1)

    int pa = 0, pb = 0;
    for (int t = 0; t < NT; t++) {
        const int par = t & 1;                 // slot holding u(t) strips
        float* uCur = uS[pa];
        float* uN   = uS[pa ^ 1];
        const float* pyO = pyS[pb];
        float*       pyN = pyS[pb ^ 1];
        const float* pxO = pxS[pb];
        float*       pxN = pxS[pb ^ 1];

        // ---- 1. spin on prefetched packed cell; write halo to LDS ----
        if (nv) {
            const int need = t + 1;
            const u64* sp = sA + (size_t)par * STAGE_CELLS;
            while ((int)(pf >> 32) < need) pf = gload64(sp);
            uCur[hLds] = __uint_as_float((unsigned)pf);
        }
        __syncthreads();                       // the ONLY barrier per step

        // ---- 2. receivers sample u(t) = un(t-1) ----
        if (t > 0 && recLds >= 0) out[recOut + (t - 1) * NREC] = uCur[recLds];

        // ---- 3. role-split fused compute + early publish ----
        u64* sb = stage + (size_t)(bid * 2 + (par ^ 1)) * STAGE_CELLS;
        if (hasTask) {
            // role 0: column direction (stride UW); role 1: row (stride 1)
            const float* uBase = role ? &uCur[(8 + y) * UW + x]
                                      : &uCur[y * UW + 8 + x];
            const int uStr = role ? 1 : UW;
            const float* pBase = role ? &pxO[y * PXW + x] : &pyO[y * TX + x];
            const int pStr = role ? 1 : TX;
            const float* bb  = role ? &bxS[x]  : &byS[y];
            const float* bbm = role ? &bxmS[x] : &bymS[y];

            float up[17];
#pragma unroll
            for (int j = 0; j < 17; j++)
                up[j] = (j == 8) ? u_curr : uBase[j * uStr];

            float pn[9];
#pragma unroll
            for (int j = 0; j < 9; j++) {
                float d1a = 0.0f, d1b = 0.0f;
#pragma unroll
                for (int k = 0; k < 4; k++) {
                    d1a = fmaf(C1D[k],     up[j + k],     d1a);
                    d1b = fmaf(C1D[k + 5], up[j + k + 5], d1b);
                }
                pn[j] = fmaf(bb[j], pBase[j * pStr], bbm[j] * (d1a + d1b));
            }

            float d2 = 0.0f, d1p = 0.0f;
#pragma unroll
            for (int k = 0; k < 9; k++) {
                d2 = fmaf(C2D[k], up[4 + k], d2);
                if (k != 4) d1p = fmaf(C1D[k], pn[k], d1p);
            }
            const float partial = d2 + d1p;
            const float other = __shfl_xor(partial, 1);  // pair exchange

            float unv = 0.0f;
            if (role == 0) {
                const float lap = partial + other;
                const float f = isSrc ? srcS[t] : 0.0f;
                unv = (Av_r * u_curr - Bv_r * u_prev + e_r * (lap + f)) * d_r;
                // early packed publish: {u(t+1), tag=t+2} from register
                const u64 pk = ((u64)(unsigned)(t + 2) << 32) |
                               (u64)__float_as_uint(unv);
                if (aN >= 0) gstore64(sb + aN, pk);
                if (aS >= 0) gstore64(sb + aS, pk);
                if (aW >= 0) gstore64(sb + aW, pk);
                if (aE >= 0) gstore64(sb + aE, pk);
            }
            const float got = __shfl_xor(unv, 1);        // unv back to role 1
            const float u_new = role ? got : unv;

            // p LDS writes (own cell + apron from redundant chain ends)
            float* pDst = role ? pxN : pyN;
            pDst[role ? (y * PXW + x + 4) : ((y + 4) * TX + x)] = pn[4];
            const int lo = role ? x : y;
            const int hiLim = role ? cols : rows;
            if (lo < 4)
                pDst[role ? (y * PXW + x) : (y * TX + x)] = pn[0];
            if (lo >= hiLim - 4)
                pDst[role ? (y * PXW + x + 8) : ((y + 8) * TX + x)] = pn[8];

            if (role == 0) uN[(8 + y) * UW + 8 + x] = unv;
            u_prev = u_curr; u_curr = u_new;
        }

        // ---- 4. prefetch next slot (overlaps MALL RT with loop tail) ----
        if (nv) pf = gload64(sA + (size_t)(par ^ 1) * STAGE_CELLS);

        pa ^= 1; pb ^= 1;
    }

    // epilogue: sample the last wavefield u(NT) = un(NT-1)
    __syncthreads();
    if (recLds >= 0) out[recOut + (NT - 1) * NREC] = uS[pa][recLds];
}

// ---------------- host launch ----------------
extern "C" void kernel_launch(void* const* d_in, const int* in_sizes, int n_in,
                              void* d_out, int out_size, void* d_ws, size_t ws_size,
                              hipStream_t stream) {
    const float* vp = (const float*)d_in[0];
    const float* src = (const float*)d_in[1];
    const int* src_loc = (const int*)d_in[2];
    const int* rec_loc = (const int*)d_in[3];
    float* out = (float*)d_out;

    float* ws = (float*)d_ws;
    float* cst = ws;                           // 32 floats (keeps stage 8B-aligned)
    u64* stage = (u64*)(ws + 32);              // NBLKS*2*STAGE_CELLS packed cells

    // zero cst + stage (tags=0; prologue publishes tag=1 cells into slot 0)
    hipMemsetAsync(d_ws, 0,
                   (size_t)32 * sizeof(float) +
                   (size_t)NBLKS * 2 * STAGE_CELLS * sizeof(u64),
                   stream);
    vmax_kernel<<<1, 256, 0, stream>>>(vp, cst);
    persist_kernel<<<NBLKS, THREADS, 0, stream>>>(
        vp, src, src_loc, rec_loc, out, stage, cst);
}